// Round 3
// baseline (97.523 us; speedup 1.0000x reference)
//
#include <hip/hip_runtime.h>
#include <math.h>

#define HDIM 256
#define H4   64          // HDIM / 4
#define EPSN 1e-8f       // torch F.cosine_similarity norm clamp
#define CT   64          // c-tile per block
#define KC   8           // f4 k-steps per chunk (32 floats)
#define NCH  8           // chunks: KC*NCH = H4

typedef unsigned long long u64;
typedef unsigned int       u32;

// Monotonic (value, index) packing: larger key == better candidate under
// lax.top_k semantics (descending value, lower index wins ties).
__device__ __forceinline__ u64 make_key(float v, int idx) {
    u32 u = __float_as_uint(v);
    u ^= (u & 0x80000000u) ? 0xFFFFFFFFu : 0x80000000u;
    return ((u64)u << 32) | (u32)(~idx);
}
__device__ __forceinline__ float key_val(u64 k) {
    u32 u = (u32)(k >> 32);
    u ^= (u & 0x80000000u) ? 0x80000000u : 0xFFFFFFFFu;
    return __uint_as_float(u);
}
__device__ __forceinline__ int key_idx(u64 k) { return (int)(~(u32)k); }

// ---------------------------------------------------------------------------
// Kernel 0 (prep): blocks 0..B-1 -> qinv[b] (one wave, butterfly reduce);
// block B -> is_compressed storage-layout flags (same detection logic that
// passed rounds 1-2: byte-offset nonzeros -> 1-byte layout, byte>1 -> f32).
// All blocks run in parallel; removes all per-block prologue work from sims.
// ---------------------------------------------------------------------------
__global__ __launch_bounds__(64)
void prep_kernel(const float4* __restrict__ q4, const u32* __restrict__ mask4,
                 int C, int B, float* __restrict__ qinv, int* __restrict__ flags) {
    const int blk  = blockIdx.x;
    const int lane = threadIdx.x;
    if (blk < B) {
        float4 v = q4[(size_t)blk * H4 + lane];
        float ss = fmaf(v.x, v.x, fmaf(v.y, v.y, fmaf(v.z, v.z, v.w * v.w)));
        #pragma unroll
        for (int off = 32; off; off >>= 1) ss += __shfl_xor(ss, off, 64);
        if (lane == 0) qinv[blk] = 1.f / fmaxf(sqrtf(ss), EPSN);
    } else {
        const int n4 = C >> 2;
        int lo = 0, lg = 0;
        for (int i = lane; i < n4; i += 64) {
            u32 v = mask4[i];
            if (v & 0xFFFFFF00u) lo = 1;   // nonzero byte at offset 1..3
            if (v & 0xFEFEFEFEu) lg = 1;   // any byte value > 1
        }
        const unsigned char* mb = (const unsigned char*)mask4;
        for (int i = (n4 << 2) + lane; i < C; i += 64) {
            unsigned char v = mb[i];
            if (v > 1) lg = 1;
            if ((i & 3) != 0 && v != 0) lo = 1;
        }
        lo = __any(lo); lg = __any(lg);
        if (lane == 0) { flags[0] = lo; flags[1] = lg; }
    }
}

// ---------------------------------------------------------------------------
// Kernel 1 (sims): 64c x 64b block tile, 4x4 register tile per lane
// (interleaved +16 row assignment), K chunked 8 x 32 floats in LDS.
// LDS rows padded to 9 f4 (144 B) -> bank = 4*(row+s) mod 32 -> the 16
// tc-lanes of an a-read land 2-way per bank group (free); b-reads are 4-addr
// broadcasts. 8 ds_read_b128 feed 80 FMA per step (10 FMA/read).
// e-norm fused on the a-frag (each lane sees its 4 c-rows' full K range).
// ---------------------------------------------------------------------------
__global__ __launch_bounds__(256)
void sims_kernel(const float4* __restrict__ q4, const float4* __restrict__ emb4,
                 const float* __restrict__ qinv, float* __restrict__ sims,
                 int C, int B) {
    __shared__ float4 e_lds[CT][KC + 1];
    __shared__ float4 q_lds[64][KC + 1];

    const int t  = threadIdx.x;
    const int c0 = blockIdx.x * CT;
    const int tc = t & 15;       // c-group: rows tc, tc+16, tc+32, tc+48
    const int tb = t >> 4;       // b-group: rows tb, tb+16, tb+32, tb+48
    const int st = t & 7;        // staging step
    const int cl = t >> 3;       // staging row 0..31 (+32 for h=1)

    float acc[4][4];
    float ee[4];
    #pragma unroll
    for (int i = 0; i < 4; ++i) {
        ee[i] = 0.f;
        #pragma unroll
        for (int j = 0; j < 4; ++j) acc[i][j] = 0.f;
    }

    const float4 z = make_float4(0.f, 0.f, 0.f, 0.f);

    for (int ch = 0; ch < NCH; ++ch) {
        __syncthreads();
        #pragma unroll
        for (int h = 0; h < 2; ++h) {
            int row = cl + 32 * h;
            int gc  = c0 + row;
            e_lds[row][st] = (gc < C)  ? emb4[(size_t)gc  * H4 + ch * KC + st] : z;
            q_lds[row][st] = (row < B) ? q4  [(size_t)row * H4 + ch * KC + st] : z;
        }
        __syncthreads();

        #pragma unroll
        for (int s = 0; s < KC; ++s) {
            float4 a0 = e_lds[tc     ][s];
            float4 a1 = e_lds[tc + 16][s];
            float4 a2 = e_lds[tc + 32][s];
            float4 a3 = e_lds[tc + 48][s];
            float4 b0 = q_lds[tb     ][s];
            float4 b1 = q_lds[tb + 16][s];
            float4 b2 = q_lds[tb + 32][s];
            float4 b3 = q_lds[tb + 48][s];

            ee[0] = fmaf(a0.x,a0.x, fmaf(a0.y,a0.y, fmaf(a0.z,a0.z, fmaf(a0.w,a0.w, ee[0]))));
            ee[1] = fmaf(a1.x,a1.x, fmaf(a1.y,a1.y, fmaf(a1.z,a1.z, fmaf(a1.w,a1.w, ee[1]))));
            ee[2] = fmaf(a2.x,a2.x, fmaf(a2.y,a2.y, fmaf(a2.z,a2.z, fmaf(a2.w,a2.w, ee[2]))));
            ee[3] = fmaf(a3.x,a3.x, fmaf(a3.y,a3.y, fmaf(a3.z,a3.z, fmaf(a3.w,a3.w, ee[3]))));

            #define DOT4(A, BV, ACC) \
                ACC = fmaf(A.x, BV.x, fmaf(A.y, BV.y, fmaf(A.z, BV.z, fmaf(A.w, BV.w, ACC))))
            DOT4(a0, b0, acc[0][0]); DOT4(a0, b1, acc[0][1]); DOT4(a0, b2, acc[0][2]); DOT4(a0, b3, acc[0][3]);
            DOT4(a1, b0, acc[1][0]); DOT4(a1, b1, acc[1][1]); DOT4(a1, b2, acc[1][2]); DOT4(a1, b3, acc[1][3]);
            DOT4(a2, b0, acc[2][0]); DOT4(a2, b1, acc[2][1]); DOT4(a2, b2, acc[2][2]); DOT4(a2, b3, acc[2][3]);
            DOT4(a3, b0, acc[3][0]); DOT4(a3, b1, acc[3][1]); DOT4(a3, b2, acc[3][2]); DOT4(a3, b3, acc[3][3]);
            #undef DOT4
        }
    }

    float einv[4];
    #pragma unroll
    for (int i = 0; i < 4; ++i) einv[i] = 1.f / fmaxf(sqrtf(ee[i]), EPSN);

    #pragma unroll
    for (int j = 0; j < 4; ++j) {
        int b = tb + 16 * j;
        if (b < B) {
            float qv = qinv[b];
            #pragma unroll
            for (int i = 0; i < 4; ++i) {
                int c = c0 + tc + 16 * i;
                if (c < C) sims[(size_t)b * C + c] = acc[i][j] * qv * einv[i];
            }
        }
    }
}

// ---------------------------------------------------------------------------
// Kernel 2: per-row top-8 via u64 keys. One block per b.
// ---------------------------------------------------------------------------
__global__ __launch_bounds__(256)
void topk_kernel(const float* __restrict__ sims,
                 float* __restrict__ scores_out,
                 int* __restrict__ idx_out, int C) {
    __shared__ u64 sh[256 * 8];   // 16 KB
    const int b = blockIdx.x, t = threadIdx.x;
    const float* row = sims + (size_t)b * C;

    u64 ls[8];
    #pragma unroll
    for (int j = 0; j < 8; ++j) ls[j] = 0ull;

    for (int c = t; c < C; c += 256) {
        u64 k = make_key(row[c], c);
        if (k > ls[7]) {
            ls[7] = k;
            #pragma unroll
            for (int j = 7; j > 0; --j)
                if (ls[j] > ls[j-1]) { u64 tmp = ls[j]; ls[j] = ls[j-1]; ls[j-1] = tmp; }
        }
    }
    #pragma unroll
    for (int j = 0; j < 8; ++j) sh[t * 8 + j] = ls[j];
    __syncthreads();

    if (t < 64) {
        u64 m[8];
        #pragma unroll
        for (int j = 0; j < 8; ++j) m[j] = 0ull;
        for (int tt = 0; tt < 4; ++tt) {
            const u64* p = &sh[(t * 4 + tt) * 8];
            #pragma unroll
            for (int j = 0; j < 8; ++j) {
                u64 k = p[j];
                if (k <= m[7]) break;           // p[] sorted descending
                m[7] = k;
                #pragma unroll
                for (int q = 7; q > 0; --q)
                    if (m[q] > m[q-1]) { u64 tmp = m[q]; m[q] = m[q-1]; m[q-1] = tmp; }
            }
        }
        for (int r = 0; r < 8; ++r) {
            u64 best = m[0];
            #pragma unroll
            for (int off = 32; off; off >>= 1) {
                u64 o = __shfl_xor(best, off, 64);
                if (o > best) best = o;
            }
            if (m[0] == best) {                 // unique owner pops
                #pragma unroll
                for (int q = 0; q < 7; ++q) m[q] = m[q+1];
                m[7] = 0ull;
            }
            if (t == 0) {
                scores_out[b * 8 + r] = key_val(best);
                idx_out[b * 8 + r]    = key_idx(best);
            }
        }
    }
}

// ---------------------------------------------------------------------------
// Kernel 3: gather. One block per (b, j): full episode OR compressed+pad.
// ---------------------------------------------------------------------------
__global__ __launch_bounds__(256)
void gather_kernel(const float* __restrict__ episodes,    // [C][S][256]
                   const float* __restrict__ compressed,  // [C][Cs][256]
                   const void* __restrict__ is_comp,
                   const int* __restrict__ top_idx,       // [B*8]
                   const int* __restrict__ flags,
                   float* __restrict__ out,               // [B*8][S*256]
                   int S, int Cs) {
    const int bj  = blockIdx.x;
    const int idx = top_idx[bj];
    const int f_off = flags[0], f_gt1 = flags[1];

    bool comp;
    if      (f_gt1) comp = ((const float*)is_comp)[idx] != 0.f;
    else if (f_off) comp = ((const unsigned char*)is_comp)[idx] != 0;
    else            comp = ((const int*)is_comp)[idx] != 0;

    const int n4 = S * H4;      // 2048
    const int c4 = Cs * H4;     // 1024
    const float4* full4 = (const float4*)episodes   + (size_t)idx * n4;
    const float4* cmp4  = (const float4*)compressed + (size_t)idx * c4;
    float4* out4 = (float4*)out + (size_t)bj * n4;
    const float4 z = make_float4(0.f, 0.f, 0.f, 0.f);

    if (comp) {
        #pragma unroll 4
        for (int v = threadIdx.x; v < n4; v += blockDim.x)
            out4[v] = (v < c4) ? cmp4[v] : z;
    } else {
        #pragma unroll 4
        for (int v = threadIdx.x; v < n4; v += blockDim.x)
            out4[v] = full4[v];
    }
}

// ---------------------------------------------------------------------------
extern "C" void kernel_launch(void* const* d_in, const int* in_sizes, int n_in,
                              void* d_out, int out_size, void* d_ws, size_t ws_size,
                              hipStream_t stream) {
    const float* query      = (const float*)d_in[0];
    const float* episodes   = (const float*)d_in[1];
    const float* compressed = (const float*)d_in[2];
    const float* emb        = (const float*)d_in[3];
    const void*  is_comp    = d_in[4];
    // d_in[5] is k (device scalar); fixed at 8 by the problem setup.

    const int B  = in_sizes[0] / HDIM;        // 64
    const int C  = in_sizes[3] / HDIM;        // 20000
    const int S  = in_sizes[1] / (C * HDIM);  // 32
    const int Cs = in_sizes[2] / (C * HDIM);  // 16
    const int K  = 8;

    float* out        = (float*)d_out;
    float* scores_out = out + (size_t)B * K * S * HDIM;

    // sims scratch lives in the retrieved-output region of d_out (5.12 MB of
    // 16.8 MB); fully consumed by topk before gather overwrites it.
    float* sims = out;

    int*   top_idx = (int*)d_ws;            // B*K ints
    int*   flags   = top_idx + B * K;       // 2 ints
    float* qinv    = (float*)(flags + 2);   // B floats

    prep_kernel<<<B + 1, 64, 0, stream>>>((const float4*)query,
                                          (const u32*)is_comp, C, B, qinv, flags);
    sims_kernel<<<(C + CT - 1) / CT, 256, 0, stream>>>(
        (const float4*)query, (const float4*)emb, qinv, sims, C, B);
    topk_kernel<<<B, 256, 0, stream>>>(sims, scores_out, top_idx, C);
    gather_kernel<<<B * K, 256, 0, stream>>>(episodes, compressed, is_comp,
                                             top_idx, flags, out, S, Cs);
}

// Round 4
// 77.854 us; speedup vs baseline: 1.2526x; 1.2526x over previous
//
#include <hip/hip_runtime.h>
#include <math.h>

#define HDIM 256
#define H4   64          // HDIM / 4
#define EPSN 1e-8f       // torch F.cosine_similarity norm clamp
#define CT   80          // c-tile per block -> grid = 250 blocks (no CU tail)
#define KC   8           // f4 k-steps per chunk (32 floats)
#define NCH  8           // chunks: KC*NCH = H4

typedef unsigned long long u64;
typedef unsigned int       u32;

// Monotonic (value, index) packing: larger key == better candidate under
// lax.top_k semantics (descending value, lower index wins ties).
__device__ __forceinline__ u64 make_key(float v, int idx) {
    u32 u = __float_as_uint(v);
    u ^= (u & 0x80000000u) ? 0xFFFFFFFFu : 0x80000000u;
    return ((u64)u << 32) | (u32)(~idx);
}
__device__ __forceinline__ float key_val(u64 k) {
    u32 u = (u32)(k >> 32);
    u ^= (u & 0x80000000u) ? 0x80000000u : 0xFFFFFFFFu;
    return __uint_as_float(u);
}
__device__ __forceinline__ int key_idx(u64 k) { return (int)(~(u32)k); }

// ---------------------------------------------------------------------------
// Kernel 1 (sims): 80c x 64b block tile, 5x4 register tile per lane.
// grid = ceil(C/80) = 250 blocks -> 1 block/CU, no tail. K chunked 8 x 32
// floats, rows padded to 9 f4. Next chunk prefetched to registers during
// compute (hides HBM latency at 4 waves/CU). e-norms AND q-norms fused into
// the accumulation (a-frag / b-frag self-dots cover each row's full K) --
// removes the prep kernel entirely.
// ---------------------------------------------------------------------------
__global__ __launch_bounds__(256)
void sims_kernel(const float4* __restrict__ q4, const float4* __restrict__ emb4,
                 float* __restrict__ sims, int C, int B) {
    __shared__ float4 e_lds[CT][KC + 1];   // 80 x 9 f4 = 11.5 KB
    __shared__ float4 q_lds[64][KC + 1];   // 64 x 9 f4 =  9.2 KB

    const int t  = threadIdx.x;
    const int c0 = blockIdx.x * CT;
    const int tc = t & 15;       // c-rows: tc + 16i, i < 5
    const int tb = t >> 4;       // b-rows: tb + 16j, j < 4
    const float4 z = make_float4(0.f, 0.f, 0.f, 0.f);

    // staging: e = 80*8 = 640 f4 (idx t, t+256, t+512 if t<128); q = 512 f4
    float4 pe0, pe1, pe2, pq0, pq1;

    #define LOAD_E(idx, ch, dst) do {                                        \
        int _r = (idx) >> 3, _cl = (idx) & 7; int _gc = c0 + _r;             \
        dst = (_gc < C) ? emb4[(size_t)_gc * H4 + (ch) * KC + _cl] : z;      \
    } while (0)
    #define LOAD_Q(idx, ch, dst) do {                                        \
        int _r = (idx) >> 3, _cl = (idx) & 7;                                \
        dst = (_r < B) ? q4[(size_t)_r * H4 + (ch) * KC + _cl] : z;          \
    } while (0)
    #define LOAD_CHUNK(ch) do {                                              \
        LOAD_E(t,       ch, pe0); LOAD_E(t + 256, ch, pe1);                  \
        if (t < 128) LOAD_E(t + 512, ch, pe2);                               \
        LOAD_Q(t,       ch, pq0); LOAD_Q(t + 256, ch, pq1);                  \
    } while (0)

    LOAD_CHUNK(0);

    float acc[5][4], ee[5], qq[4];
    #pragma unroll
    for (int i = 0; i < 5; ++i) {
        ee[i] = 0.f;
        #pragma unroll
        for (int j = 0; j < 4; ++j) acc[i][j] = 0.f;
    }
    #pragma unroll
    for (int j = 0; j < 4; ++j) qq[j] = 0.f;

    for (int ch = 0; ch < NCH; ++ch) {
        __syncthreads();                       // prev chunk's LDS reads done
        { int r = t >> 3,        cl = t & 7;        e_lds[r][cl] = pe0; }
        { int r = (t+256) >> 3,  cl = (t+256) & 7;  e_lds[r][cl] = pe1; }
        if (t < 128) { int r = (t+512) >> 3, cl = (t+512) & 7; e_lds[r][cl] = pe2; }
        { int r = t >> 3,        cl = t & 7;        q_lds[r][cl] = pq0; }
        { int r = (t+256) >> 3,  cl = (t+256) & 7;  q_lds[r][cl] = pq1; }
        __syncthreads();                       // stores visible

        if (ch + 1 < NCH) LOAD_CHUNK(ch + 1);  // prefetch overlaps compute

        #pragma unroll
        for (int s = 0; s < KC; ++s) {
            float4 a[5], b[4];
            #pragma unroll
            for (int i = 0; i < 5; ++i) a[i] = e_lds[tc + 16 * i][s];
            #pragma unroll
            for (int j = 0; j < 4; ++j) b[j] = q_lds[tb + 16 * j][s];

            #pragma unroll
            for (int i = 0; i < 5; ++i)
                ee[i] = fmaf(a[i].x,a[i].x, fmaf(a[i].y,a[i].y,
                        fmaf(a[i].z,a[i].z, fmaf(a[i].w,a[i].w, ee[i]))));
            #pragma unroll
            for (int j = 0; j < 4; ++j)
                qq[j] = fmaf(b[j].x,b[j].x, fmaf(b[j].y,b[j].y,
                        fmaf(b[j].z,b[j].z, fmaf(b[j].w,b[j].w, qq[j]))));
            #pragma unroll
            for (int i = 0; i < 5; ++i)
                #pragma unroll
                for (int j = 0; j < 4; ++j)
                    acc[i][j] = fmaf(a[i].x,b[j].x, fmaf(a[i].y,b[j].y,
                                fmaf(a[i].z,b[j].z, fmaf(a[i].w,b[j].w, acc[i][j]))));
        }
    }

    float einv[5], qinv[4];
    #pragma unroll
    for (int i = 0; i < 5; ++i) einv[i] = 1.f / fmaxf(sqrtf(ee[i]), EPSN);
    #pragma unroll
    for (int j = 0; j < 4; ++j) qinv[j] = 1.f / fmaxf(sqrtf(qq[j]), EPSN);

    #pragma unroll
    for (int j = 0; j < 4; ++j) {
        int b = tb + 16 * j;
        if (b < B) {
            #pragma unroll
            for (int i = 0; i < 5; ++i) {
                int c = c0 + tc + 16 * i;
                if (c < C) sims[(size_t)b * C + c] = acc[i][j] * qinv[j] * einv[i];
            }
        }
    }
    #undef LOAD_CHUNK
    #undef LOAD_Q
    #undef LOAD_E
}

// ---------------------------------------------------------------------------
// Kernel 2: blocks 0..B-1: per-row top-8 via u64 keys (single barrier, wave-0
// shfl-butterfly merge). Last block: is_compressed storage-layout detection
// (same logic that passed rounds 1-3), 256 threads, runs in parallel.
// ---------------------------------------------------------------------------
__global__ __launch_bounds__(256)
void topk_kernel(const float* __restrict__ sims, const u32* __restrict__ mask4,
                 float* __restrict__ scores_out, int* __restrict__ idx_out,
                 int* __restrict__ flags, int C) {
    const int t = threadIdx.x;

    if (blockIdx.x == gridDim.x - 1) {     // ---- mask layout detection ----
        __shared__ int red0[4], red1[4];
        int lo = 0, lg = 0;
        const int n4 = C >> 2;
        for (int i = t; i < n4; i += 256) {
            u32 v = mask4[i];
            if (v & 0xFFFFFF00u) lo = 1;   // nonzero byte at offset 1..3
            if (v & 0xFEFEFEFEu) lg = 1;   // any byte value > 1
        }
        const unsigned char* mb = (const unsigned char*)mask4;
        for (int i = (n4 << 2) + t; i < C; i += 256) {
            unsigned char v = mb[i];
            if (v > 1) lg = 1;
            if ((i & 3) != 0 && v != 0) lo = 1;
        }
        lo = __any(lo); lg = __any(lg);
        if ((t & 63) == 0) { red0[t >> 6] = lo; red1[t >> 6] = lg; }
        __syncthreads();
        if (t == 0) {
            flags[0] = red0[0] | red0[1] | red0[2] | red0[3];
            flags[1] = red1[0] | red1[1] | red1[2] | red1[3];
        }
        return;
    }

    __shared__ u64 sh[256 * 8];   // 16 KB
    const int b = blockIdx.x;
    const float* row = sims + (size_t)b * C;

    u64 ls[8];
    #pragma unroll
    for (int j = 0; j < 8; ++j) ls[j] = 0ull;

    for (int c = t; c < C; c += 256) {
        u64 k = make_key(row[c], c);
        if (k > ls[7]) {
            ls[7] = k;
            #pragma unroll
            for (int j = 7; j > 0; --j)
                if (ls[j] > ls[j-1]) { u64 tmp = ls[j]; ls[j] = ls[j-1]; ls[j-1] = tmp; }
        }
    }
    #pragma unroll
    for (int j = 0; j < 8; ++j) sh[t * 8 + j] = ls[j];
    __syncthreads();

    if (t < 64) {
        u64 m[8];
        #pragma unroll
        for (int j = 0; j < 8; ++j) m[j] = 0ull;
        for (int tt = 0; tt < 4; ++tt) {
            const u64* p = &sh[(t * 4 + tt) * 8];
            #pragma unroll
            for (int j = 0; j < 8; ++j) {
                u64 k = p[j];
                if (k <= m[7]) break;           // p[] sorted descending
                m[7] = k;
                #pragma unroll
                for (int q = 7; q > 0; --q)
                    if (m[q] > m[q-1]) { u64 tmp = m[q]; m[q] = m[q-1]; m[q-1] = tmp; }
            }
        }
        for (int r = 0; r < 8; ++r) {
            u64 best = m[0];
            #pragma unroll
            for (int off = 32; off; off >>= 1) {
                u64 o = __shfl_xor(best, off, 64);
                if (o > best) best = o;
            }
            if (m[0] == best) {                 // unique owner pops
                #pragma unroll
                for (int q = 0; q < 7; ++q) m[q] = m[q+1];
                m[7] = 0ull;
            }
            if (t == 0) {
                scores_out[b * 8 + r] = key_val(best);
                idx_out[b * 8 + r]    = key_idx(best);
            }
        }
    }
}

// ---------------------------------------------------------------------------
// Kernel 3: gather. One block per (b, j): full episode OR compressed+pad.
// ---------------------------------------------------------------------------
__global__ __launch_bounds__(256)
void gather_kernel(const float* __restrict__ episodes,    // [C][S][256]
                   const float* __restrict__ compressed,  // [C][Cs][256]
                   const void* __restrict__ is_comp,
                   const int* __restrict__ top_idx,       // [B*8]
                   const int* __restrict__ flags,
                   float* __restrict__ out,               // [B*8][S*256]
                   int S, int Cs) {
    const int bj  = blockIdx.x;
    const int idx = top_idx[bj];
    const int f_off = flags[0], f_gt1 = flags[1];

    bool comp;
    if      (f_gt1) comp = ((const float*)is_comp)[idx] != 0.f;
    else if (f_off) comp = ((const unsigned char*)is_comp)[idx] != 0;
    else            comp = ((const int*)is_comp)[idx] != 0;

    const int n4 = S * H4;      // 2048
    const int c4 = Cs * H4;     // 1024
    const float4* full4 = (const float4*)episodes   + (size_t)idx * n4;
    const float4* cmp4  = (const float4*)compressed + (size_t)idx * c4;
    float4* out4 = (float4*)out + (size_t)bj * n4;
    const float4 z = make_float4(0.f, 0.f, 0.f, 0.f);

    if (comp) {
        #pragma unroll 4
        for (int v = threadIdx.x; v < n4; v += blockDim.x)
            out4[v] = (v < c4) ? cmp4[v] : z;
    } else {
        #pragma unroll 4
        for (int v = threadIdx.x; v < n4; v += blockDim.x)
            out4[v] = full4[v];
    }
}

// ---------------------------------------------------------------------------
extern "C" void kernel_launch(void* const* d_in, const int* in_sizes, int n_in,
                              void* d_out, int out_size, void* d_ws, size_t ws_size,
                              hipStream_t stream) {
    const float* query      = (const float*)d_in[0];
    const float* episodes   = (const float*)d_in[1];
    const float* compressed = (const float*)d_in[2];
    const float* emb        = (const float*)d_in[3];
    const void*  is_comp    = d_in[4];
    // d_in[5] is k (device scalar); fixed at 8 by the problem setup.

    const int B  = in_sizes[0] / HDIM;        // 64
    const int C  = in_sizes[3] / HDIM;        // 20000
    const int S  = in_sizes[1] / (C * HDIM);  // 32
    const int Cs = in_sizes[2] / (C * HDIM);  // 16
    const int K  = 8;

    float* out        = (float*)d_out;
    float* scores_out = out + (size_t)B * K * S * HDIM;

    // scratch layout in d_ws (fully rewritten every call -> deterministic):
    float* sims    = (float*)d_ws;                             // B*C floats
    size_t simsOff = (((size_t)B * C * sizeof(float)) + 255) & ~(size_t)255;
    int*   top_idx = (int*)((char*)d_ws + simsOff);            // B*K ints
    int*   flags   = top_idx + B * K;                          // 2 ints

    sims_kernel<<<(C + CT - 1) / CT, 256, 0, stream>>>(
        (const float4*)query, (const float4*)emb, sims, C, B);
    topk_kernel<<<B + 1, 256, 0, stream>>>(sims, (const u32*)is_comp,
                                           scores_out, top_idx, flags, C);
    gather_kernel<<<B * K, 256, 0, stream>>>(episodes, compressed, is_comp,
                                             top_idx, flags, out, S, Cs);
}

// Round 5
// 67.824 us; speedup vs baseline: 1.4379x; 1.1479x over previous
//
#include <hip/hip_runtime.h>
#include <math.h>

#define HDIM 256
#define H4   64          // HDIM / 4
#define EPSN 1e-8f       // torch F.cosine_similarity norm clamp
#define CT   80          // c-tile per block -> grid = 250 blocks (no CU tail)
#define KC   8           // f4 k-steps per chunk (32 floats)
#define NCH  8           // chunks: KC*NCH = H4

typedef unsigned long long u64;
typedef unsigned int       u32;

// Monotonic (value, index) packing: larger key == better candidate under
// lax.top_k semantics (descending value, lower index wins ties).
__device__ __forceinline__ u64 make_key(float v, int idx) {
    u32 u = __float_as_uint(v);
    u ^= (u & 0x80000000u) ? 0xFFFFFFFFu : 0x80000000u;
    return ((u64)u << 32) | (u32)(~idx);
}
__device__ __forceinline__ float key_val(u64 k) {
    u32 u = (u32)(k >> 32);
    u ^= (u & 0x80000000u) ? 0x80000000u : 0xFFFFFFFFu;
    return __uint_as_float(u);
}
__device__ __forceinline__ int key_idx(u64 k) { return (int)(~(u32)k); }

// ---------------------------------------------------------------------------
// Kernel 1 (sims): 80c x 64b block tile, 5x4 register tile per lane.
// grid = 250 blocks -> 1 block/CU, no tail. K chunked 8 x 32 floats, rows
// padded to 9 f4. Next chunk prefetched to registers during compute. e-norms
// and q-norms fused into the accumulation. (Unchanged from round 4.)
// ---------------------------------------------------------------------------
__global__ __launch_bounds__(256)
void sims_kernel(const float4* __restrict__ q4, const float4* __restrict__ emb4,
                 float* __restrict__ sims, int C, int B) {
    __shared__ float4 e_lds[CT][KC + 1];   // 80 x 9 f4 = 11.5 KB
    __shared__ float4 q_lds[64][KC + 1];   // 64 x 9 f4 =  9.2 KB

    const int t  = threadIdx.x;
    const int c0 = blockIdx.x * CT;
    const int tc = t & 15;       // c-rows: tc + 16i, i < 5
    const int tb = t >> 4;       // b-rows: tb + 16j, j < 4
    const float4 z = make_float4(0.f, 0.f, 0.f, 0.f);

    float4 pe0, pe1, pe2, pq0, pq1;

    #define LOAD_E(idx, ch, dst) do {                                        \
        int _r = (idx) >> 3, _cl = (idx) & 7; int _gc = c0 + _r;             \
        dst = (_gc < C) ? emb4[(size_t)_gc * H4 + (ch) * KC + _cl] : z;      \
    } while (0)
    #define LOAD_Q(idx, ch, dst) do {                                        \
        int _r = (idx) >> 3, _cl = (idx) & 7;                                \
        dst = (_r < B) ? q4[(size_t)_r * H4 + (ch) * KC + _cl] : z;          \
    } while (0)
    #define LOAD_CHUNK(ch) do {                                              \
        LOAD_E(t,       ch, pe0); LOAD_E(t + 256, ch, pe1);                  \
        if (t < 128) LOAD_E(t + 512, ch, pe2);                               \
        LOAD_Q(t,       ch, pq0); LOAD_Q(t + 256, ch, pq1);                  \
    } while (0)

    LOAD_CHUNK(0);

    float acc[5][4], ee[5], qq[4];
    #pragma unroll
    for (int i = 0; i < 5; ++i) {
        ee[i] = 0.f;
        #pragma unroll
        for (int j = 0; j < 4; ++j) acc[i][j] = 0.f;
    }
    #pragma unroll
    for (int j = 0; j < 4; ++j) qq[j] = 0.f;

    for (int ch = 0; ch < NCH; ++ch) {
        __syncthreads();                       // prev chunk's LDS reads done
        { int r = t >> 3,        cl = t & 7;        e_lds[r][cl] = pe0; }
        { int r = (t+256) >> 3,  cl = (t+256) & 7;  e_lds[r][cl] = pe1; }
        if (t < 128) { int r = (t+512) >> 3, cl = (t+512) & 7; e_lds[r][cl] = pe2; }
        { int r = t >> 3,        cl = t & 7;        q_lds[r][cl] = pq0; }
        { int r = (t+256) >> 3,  cl = (t+256) & 7;  q_lds[r][cl] = pq1; }
        __syncthreads();                       // stores visible

        if (ch + 1 < NCH) LOAD_CHUNK(ch + 1);  // prefetch overlaps compute

        #pragma unroll
        for (int s = 0; s < KC; ++s) {
            float4 a[5], b[4];
            #pragma unroll
            for (int i = 0; i < 5; ++i) a[i] = e_lds[tc + 16 * i][s];
            #pragma unroll
            for (int j = 0; j < 4; ++j) b[j] = q_lds[tb + 16 * j][s];

            #pragma unroll
            for (int i = 0; i < 5; ++i)
                ee[i] = fmaf(a[i].x,a[i].x, fmaf(a[i].y,a[i].y,
                        fmaf(a[i].z,a[i].z, fmaf(a[i].w,a[i].w, ee[i]))));
            #pragma unroll
            for (int j = 0; j < 4; ++j)
                qq[j] = fmaf(b[j].x,b[j].x, fmaf(b[j].y,b[j].y,
                        fmaf(b[j].z,b[j].z, fmaf(b[j].w,b[j].w, qq[j]))));
            #pragma unroll
            for (int i = 0; i < 5; ++i)
                #pragma unroll
                for (int j = 0; j < 4; ++j)
                    acc[i][j] = fmaf(a[i].x,b[j].x, fmaf(a[i].y,b[j].y,
                                fmaf(a[i].z,b[j].z, fmaf(a[i].w,b[j].w, acc[i][j]))));
        }
    }

    float einv[5], qinv[4];
    #pragma unroll
    for (int i = 0; i < 5; ++i) einv[i] = 1.f / fmaxf(sqrtf(ee[i]), EPSN);
    #pragma unroll
    for (int j = 0; j < 4; ++j) qinv[j] = 1.f / fmaxf(sqrtf(qq[j]), EPSN);

    #pragma unroll
    for (int j = 0; j < 4; ++j) {
        int b = tb + 16 * j;
        if (b < B) {
            #pragma unroll
            for (int i = 0; i < 5; ++i) {
                int c = c0 + tc + 16 * i;
                if (c < C) sims[(size_t)b * C + c] = acc[i][j] * qinv[j] * einv[i];
            }
        }
    }
    #undef LOAD_CHUNK
    #undef LOAD_Q
    #undef LOAD_E
}

// ---------------------------------------------------------------------------
// Kernel 2: blocks 0..B-1: per-row top-8. Scan phase uses 8-deep manual load
// batching (8 independent global loads -> regs, THEN the branchy insert pass)
// so the insertion-sort control flow no longer serializes memory latency.
// Last block: is_compressed storage-layout detection (4-deep batched).
// ---------------------------------------------------------------------------
__global__ __launch_bounds__(256)
void topk_kernel(const float* __restrict__ sims, const u32* __restrict__ mask4,
                 float* __restrict__ scores_out, int* __restrict__ idx_out,
                 int* __restrict__ flags, int C) {
    const int t = threadIdx.x;

    if (blockIdx.x == gridDim.x - 1) {     // ---- mask layout detection ----
        __shared__ int red0[4], red1[4];
        int lo = 0, lg = 0;
        const int n4 = C >> 2;
        int i = t;
        for (; i + 768 < n4; i += 1024) {
            u32 v0 = mask4[i], v1 = mask4[i + 256], v2 = mask4[i + 512], v3 = mask4[i + 768];
            u32 o = v0 | v1 | v2 | v3;
            if (o & 0xFFFFFF00u) lo = 1;   // nonzero byte at offset 1..3
            if (o & 0xFEFEFEFEu) lg = 1;   // any byte value > 1
        }
        for (; i < n4; i += 256) {
            u32 v = mask4[i];
            if (v & 0xFFFFFF00u) lo = 1;
            if (v & 0xFEFEFEFEu) lg = 1;
        }
        const unsigned char* mb = (const unsigned char*)mask4;
        for (int j = (n4 << 2) + t; j < C; j += 256) {
            unsigned char v = mb[j];
            if (v > 1) lg = 1;
            if ((j & 3) != 0 && v != 0) lo = 1;
        }
        lo = __any(lo); lg = __any(lg);
        if ((t & 63) == 0) { red0[t >> 6] = lo; red1[t >> 6] = lg; }
        __syncthreads();
        if (t == 0) {
            flags[0] = red0[0] | red0[1] | red0[2] | red0[3];
            flags[1] = red1[0] | red1[1] | red1[2] | red1[3];
        }
        return;
    }

    __shared__ u64 sh[256 * 8];   // 16 KB
    const int b = blockIdx.x;
    const float* row = sims + (size_t)b * C;

    u64 ls[8];
    #pragma unroll
    for (int j = 0; j < 8; ++j) ls[j] = 0ull;

    #define INSERT(KEY) do {                                                  \
        u64 _k = (KEY);                                                       \
        if (_k > ls[7]) {                                                     \
            ls[7] = _k;                                                       \
            _Pragma("unroll")                                                 \
            for (int _j = 7; _j > 0; --_j)                                    \
                if (ls[_j] > ls[_j-1]) { u64 _t = ls[_j]; ls[_j] = ls[_j-1]; ls[_j-1] = _t; } \
        }                                                                     \
    } while (0)

    int c = t;
    for (; c + 7 * 256 < C; c += 8 * 256) {        // 8 independent loads first
        float v[8];
        #pragma unroll
        for (int u = 0; u < 8; ++u) v[u] = row[c + u * 256];
        #pragma unroll
        for (int u = 0; u < 8; ++u) INSERT(make_key(v[u], c + u * 256));
    }
    for (; c < C; c += 256) INSERT(make_key(row[c], c));
    #undef INSERT

    #pragma unroll
    for (int j = 0; j < 8; ++j) sh[t * 8 + j] = ls[j];
    __syncthreads();

    if (t < 64) {
        u64 m[8];
        #pragma unroll
        for (int j = 0; j < 8; ++j) m[j] = 0ull;
        for (int tt = 0; tt < 4; ++tt) {
            const u64* p = &sh[(t * 4 + tt) * 8];
            #pragma unroll
            for (int j = 0; j < 8; ++j) {
                u64 k = p[j];
                if (k <= m[7]) break;           // p[] sorted descending
                m[7] = k;
                #pragma unroll
                for (int q = 7; q > 0; --q)
                    if (m[q] > m[q-1]) { u64 tmp = m[q]; m[q] = m[q-1]; m[q-1] = tmp; }
            }
        }
        for (int r = 0; r < 8; ++r) {
            u64 best = m[0];
            #pragma unroll
            for (int off = 32; off; off >>= 1) {
                u64 o = __shfl_xor(best, off, 64);
                if (o > best) best = o;
            }
            if (m[0] == best) {                 // unique owner pops
                #pragma unroll
                for (int q = 0; q < 7; ++q) m[q] = m[q+1];
                m[7] = 0ull;
            }
            if (t == 0) {
                scores_out[b * 8 + r] = key_val(best);
                idx_out[b * 8 + r]    = key_idx(best);
            }
        }
    }
}

// ---------------------------------------------------------------------------
// Kernel 3: gather. TWO blocks per (b, j): each copies half an episode
// (1024 f4 = 16 KB), 4 independent f4 loads per thread. For compressed
// episodes, half 0 is exactly the compressed payload, half 1 is zeros.
// ---------------------------------------------------------------------------
__global__ __launch_bounds__(256)
void gather_kernel(const float* __restrict__ episodes,    // [C][S][256]
                   const float* __restrict__ compressed,  // [C][Cs][256]
                   const void* __restrict__ is_comp,
                   const int* __restrict__ top_idx,       // [B*8]
                   const int* __restrict__ flags,
                   float* __restrict__ out,               // [B*8][S*256]
                   int S, int Cs) {
    const int bj  = blockIdx.x >> 1;
    const int h   = blockIdx.x & 1;
    const int idx = top_idx[bj];
    const int f_off = flags[0], f_gt1 = flags[1];

    bool comp;
    if      (f_gt1) comp = ((const float*)is_comp)[idx] != 0.f;
    else if (f_off) comp = ((const unsigned char*)is_comp)[idx] != 0;
    else            comp = ((const int*)is_comp)[idx] != 0;

    const int n4   = S * H4;       // 2048
    const int c4   = Cs * H4;      // 1024
    const int half = n4 >> 1;      // 1024
    const int v0   = h * half;     // this block's range [v0, v0+half)

    const float4* full4 = (const float4*)episodes   + (size_t)idx * n4;
    const float4* cmp4  = (const float4*)compressed + (size_t)idx * c4;
    float4* out4 = (float4*)out + (size_t)bj * n4;
    const float4 z = make_float4(0.f, 0.f, 0.f, 0.f);

    if (comp) {
        #pragma unroll 4
        for (int v = v0 + threadIdx.x; v < v0 + half; v += 256)
            out4[v] = (v < c4) ? cmp4[v] : z;
    } else {
        #pragma unroll 4
        for (int v = v0 + threadIdx.x; v < v0 + half; v += 256)
            out4[v] = full4[v];
    }
}

// ---------------------------------------------------------------------------
extern "C" void kernel_launch(void* const* d_in, const int* in_sizes, int n_in,
                              void* d_out, int out_size, void* d_ws, size_t ws_size,
                              hipStream_t stream) {
    const float* query      = (const float*)d_in[0];
    const float* episodes   = (const float*)d_in[1];
    const float* compressed = (const float*)d_in[2];
    const float* emb        = (const float*)d_in[3];
    const void*  is_comp    = d_in[4];
    // d_in[5] is k (device scalar); fixed at 8 by the problem setup.

    const int B  = in_sizes[0] / HDIM;        // 64
    const int C  = in_sizes[3] / HDIM;        // 20000
    const int S  = in_sizes[1] / (C * HDIM);  // 32
    const int Cs = in_sizes[2] / (C * HDIM);  // 16
    const int K  = 8;

    float* out        = (float*)d_out;
    float* scores_out = out + (size_t)B * K * S * HDIM;

    // scratch layout in d_ws (fully rewritten every call -> deterministic):
    float* sims    = (float*)d_ws;                             // B*C floats
    size_t simsOff = (((size_t)B * C * sizeof(float)) + 255) & ~(size_t)255;
    int*   top_idx = (int*)((char*)d_ws + simsOff);            // B*K ints
    int*   flags   = top_idx + B * K;                          // 2 ints

    sims_kernel<<<(C + CT - 1) / CT, 256, 0, stream>>>(
        (const float4*)query, (const float4*)emb, sims, C, B);
    topk_kernel<<<B + 1, 256, 0, stream>>>(sims, (const u32*)is_comp,
                                           scores_out, top_idx, flags, C);
    gather_kernel<<<B * K * 2, 256, 0, stream>>>(episodes, compressed, is_comp,
                                                 top_idx, flags, out, S, Cs);
}